// Round 1
// baseline (17514.258 us; speedup 1.0000x reference)
//
#include <hip/hip_runtime.h>

#define N_NODES 500000
#define N_EDGES 16000000

// ---------------------------------------------------------------------------
// Scatter: agg[dst] += h[src], DIN floats per node. One thread per edge.
// ---------------------------------------------------------------------------
template<int DIN>
__global__ __launch_bounds__(256) void scatter_add_kernel(
    const int* __restrict__ src,
    const int* __restrict__ dst,
    const float* __restrict__ h,
    float* __restrict__ agg)
{
    int e = blockIdx.x * blockDim.x + threadIdx.x;
    if (e >= N_EDGES) return;
    int s = src[e];
    int d = dst[e];
    const float* hp = h + (long)s * DIN;
    float* ap = agg + (long)d * DIN;
    float v[DIN];
#pragma unroll
    for (int k = 0; k < DIN; ++k) v[k] = hp[k];
#pragma unroll
    for (int k = 0; k < DIN; ++k) atomicAdd(ap + k, v[k]);
}

// ---------------------------------------------------------------------------
// Per-node transform: hout = relu(agg @ Wrel + brel + hin @ Wroot)
// Weights staged in LDS (uniform reads broadcast, no conflicts).
// ---------------------------------------------------------------------------
template<int DIN, int DOUT>
__global__ __launch_bounds__(256) void transform_kernel(
    const float* __restrict__ agg,
    const float* __restrict__ hin,
    const float* __restrict__ Wrel,   // [DIN][DOUT]
    const float* __restrict__ brel,   // [DOUT]
    const float* __restrict__ Wroot,  // [DIN][DOUT]
    float* __restrict__ hout)
{
    __shared__ float sWrel[DIN * DOUT];
    __shared__ float sWroot[DIN * DOUT];
    __shared__ float sbrel[DOUT];
    for (int t = threadIdx.x; t < DIN * DOUT; t += blockDim.x) {
        sWrel[t] = Wrel[t];
        sWroot[t] = Wroot[t];
    }
    for (int t = threadIdx.x; t < DOUT; t += blockDim.x) sbrel[t] = brel[t];
    __syncthreads();

    int i = blockIdx.x * blockDim.x + threadIdx.x;
    if (i >= N_NODES) return;

    float a[DIN], x[DIN];
#pragma unroll
    for (int k = 0; k < DIN; ++k) {
        a[k] = agg[(long)i * DIN + k];
        x[k] = hin[(long)i * DIN + k];
    }
#pragma unroll
    for (int o = 0; o < DOUT; ++o) {
        float v = sbrel[o];
#pragma unroll
        for (int k = 0; k < DIN; ++k)
            v += a[k] * sWrel[k * DOUT + o] + x[k] * sWroot[k * DOUT + o];
        hout[(long)i * DOUT + o] = fmaxf(v, 0.0f);
    }
}

// ---------------------------------------------------------------------------
// Fused layer-4 transform + 3-layer MLP. All weights in LDS (~6.7 KB).
// h4 = relu(agg@Wrel + brel + h3@Wroot)      [10 -> 16]
// m1 = relu(h4 @ fc1W + fc1b)                [16 -> 32]
// m2 = relu(m1 @ fc2W + fc2b)                [32 -> 16]
// out = m2 @ fc3W + fc3b                     [16 -> 16]
// ---------------------------------------------------------------------------
__global__ __launch_bounds__(256) void layer4_mlp_kernel(
    const float* __restrict__ agg,
    const float* __restrict__ h3,
    const float* __restrict__ g4Wrel,   // [10][16]
    const float* __restrict__ g4brel,   // [16]
    const float* __restrict__ g4Wroot,  // [10][16]
    const float* __restrict__ fc1W,     // [16][32]
    const float* __restrict__ fc1b,     // [32]
    const float* __restrict__ fc2W,     // [32][16]
    const float* __restrict__ fc2b,     // [16]
    const float* __restrict__ fc3W,     // [16][16]
    const float* __restrict__ fc3b,     // [16]
    float* __restrict__ out)
{
    __shared__ float s[1680];
    float* sWrel  = s;            // 160
    float* sbrel  = s + 160;      // 16
    float* sWroot = s + 176;      // 160
    float* sfc1W  = s + 336;      // 512
    float* sfc1b  = s + 848;      // 32
    float* sfc2W  = s + 880;      // 512
    float* sfc2b  = s + 1392;     // 16
    float* sfc3W  = s + 1408;     // 256
    float* sfc3b  = s + 1664;     // 16

    for (int t = threadIdx.x; t < 160; t += blockDim.x) { sWrel[t] = g4Wrel[t]; sWroot[t] = g4Wroot[t]; }
    for (int t = threadIdx.x; t < 512; t += blockDim.x) { sfc1W[t] = fc1W[t]; sfc2W[t] = fc2W[t]; }
    for (int t = threadIdx.x; t < 256; t += blockDim.x) { sfc3W[t] = fc3W[t]; }
    for (int t = threadIdx.x; t < 32;  t += blockDim.x) { sfc1b[t] = fc1b[t]; }
    for (int t = threadIdx.x; t < 16;  t += blockDim.x) { sbrel[t] = g4brel[t]; sfc2b[t] = fc2b[t]; sfc3b[t] = fc3b[t]; }
    __syncthreads();

    int i = blockIdx.x * blockDim.x + threadIdx.x;
    if (i >= N_NODES) return;

    float a[10], x[10];
#pragma unroll
    for (int k = 0; k < 10; ++k) {
        a[k] = agg[(long)i * 10 + k];
        x[k] = h3[(long)i * 10 + k];
    }

    float h4[16];
#pragma unroll
    for (int o = 0; o < 16; ++o) {
        float v = sbrel[o];
#pragma unroll
        for (int k = 0; k < 10; ++k)
            v += a[k] * sWrel[k * 16 + o] + x[k] * sWroot[k * 16 + o];
        h4[o] = fmaxf(v, 0.0f);
    }

    float m1[32];
#pragma unroll
    for (int o = 0; o < 32; ++o) {
        float v = sfc1b[o];
#pragma unroll
        for (int k = 0; k < 16; ++k) v += h4[k] * sfc1W[k * 32 + o];
        m1[o] = fmaxf(v, 0.0f);
    }

    float m2[16];
#pragma unroll
    for (int o = 0; o < 16; ++o) {
        float v = sfc2b[o];
#pragma unroll
        for (int k = 0; k < 32; ++k) v += m1[k] * sfc2W[k * 16 + o];
        m2[o] = fmaxf(v, 0.0f);
    }

    float r[16];
#pragma unroll
    for (int o = 0; o < 16; ++o) {
        float v = sfc3b[o];
#pragma unroll
        for (int k = 0; k < 16; ++k) v += m2[k] * sfc3W[k * 16 + o];
        r[o] = v;
    }
    // vectorized 16B stores: out row is 64B, 16B-aligned
    float4* op = (float4*)(out + (long)i * 16);
#pragma unroll
    for (int q = 0; q < 4; ++q)
        op[q] = make_float4(r[q * 4 + 0], r[q * 4 + 1], r[q * 4 + 2], r[q * 4 + 3]);
}

// ---------------------------------------------------------------------------
extern "C" void kernel_launch(void* const* d_in, const int* in_sizes, int n_in,
                              void* d_out, int out_size, void* d_ws, size_t ws_size,
                              hipStream_t stream) {
    const float* x        = (const float*)d_in[0];
    const int*   ei       = (const int*)d_in[1];
    const float* g1_Wrel  = (const float*)d_in[2];
    const float* g1_brel  = (const float*)d_in[3];
    const float* g1_Wroot = (const float*)d_in[4];
    const float* g2_Wrel  = (const float*)d_in[5];
    const float* g2_brel  = (const float*)d_in[6];
    const float* g2_Wroot = (const float*)d_in[7];
    const float* g3_Wrel  = (const float*)d_in[8];
    const float* g3_brel  = (const float*)d_in[9];
    const float* g3_Wroot = (const float*)d_in[10];
    const float* g4_Wrel  = (const float*)d_in[11];
    const float* g4_brel  = (const float*)d_in[12];
    const float* g4_Wroot = (const float*)d_in[13];
    const float* fc1_W    = (const float*)d_in[14];
    const float* fc1_b    = (const float*)d_in[15];
    const float* fc2_W    = (const float*)d_in[16];
    const float* fc2_b    = (const float*)d_in[17];
    const float* fc3_W    = (const float*)d_in[18];
    const float* fc3_b    = (const float*)d_in[19];
    float* out = (float*)d_out;

    const int* srcp = ei;
    const int* dstp = ei + N_EDGES;

    // Workspace layout (floats):
    //   h1 : N*4   (8 MB)
    //   h2 : N*7   (14 MB)
    //   h3 : N*10  (20 MB)
    //   agg: N*10  (20 MB, reused each layer)
    char* wsb = (char*)d_ws;
    float* h1  = (float*)(wsb);
    float* h2  = (float*)(wsb + (size_t)N_NODES * 4 * 4);
    float* h3  = (float*)(wsb + (size_t)N_NODES * (4 + 7) * 4);
    float* agg = (float*)(wsb + (size_t)N_NODES * (4 + 7 + 10) * 4);

    const int TB = 256;
    const int edge_blocks = (N_EDGES + TB - 1) / TB;
    const int node_blocks = (N_NODES + TB - 1) / TB;

    // ---- layer 1: din=1, dout=4 ----
    hipMemsetAsync(agg, 0, (size_t)N_NODES * 1 * 4, stream);
    scatter_add_kernel<1><<<edge_blocks, TB, 0, stream>>>(srcp, dstp, x, agg);
    transform_kernel<1, 4><<<node_blocks, TB, 0, stream>>>(agg, x, g1_Wrel, g1_brel, g1_Wroot, h1);

    // ---- layer 2: din=4, dout=7 ----
    hipMemsetAsync(agg, 0, (size_t)N_NODES * 4 * 4, stream);
    scatter_add_kernel<4><<<edge_blocks, TB, 0, stream>>>(srcp, dstp, h1, agg);
    transform_kernel<4, 7><<<node_blocks, TB, 0, stream>>>(agg, h1, g2_Wrel, g2_brel, g2_Wroot, h2);

    // ---- layer 3: din=7, dout=10 ----
    hipMemsetAsync(agg, 0, (size_t)N_NODES * 7 * 4, stream);
    scatter_add_kernel<7><<<edge_blocks, TB, 0, stream>>>(srcp, dstp, h2, agg);
    transform_kernel<7, 10><<<node_blocks, TB, 0, stream>>>(agg, h2, g3_Wrel, g3_brel, g3_Wroot, h3);

    // ---- layer 4 + MLP (fused) ----
    hipMemsetAsync(agg, 0, (size_t)N_NODES * 10 * 4, stream);
    scatter_add_kernel<10><<<edge_blocks, TB, 0, stream>>>(srcp, dstp, h3, agg);
    layer4_mlp_kernel<<<node_blocks, TB, 0, stream>>>(
        agg, h3, g4_Wrel, g4_brel, g4_Wroot,
        fc1_W, fc1_b, fc2_W, fc2_b, fc3_W, fc3_b, out);
}

// Round 2
// 2673.032 us; speedup vs baseline: 6.5522x; 6.5522x over previous
//
#include <hip/hip_runtime.h>

#define N_NODES 500000
#define N_EDGES 16000000
#define SCAN_CHUNK 2048
#define SCAN_NB ((N_NODES + SCAN_CHUNK - 1) / SCAN_CHUNK)   // 245

// ---------------------------------------------------------------------------
// CSR build: histogram -> scan -> cursor scatter
// ---------------------------------------------------------------------------
__global__ __launch_bounds__(256) void hist_kernel(
    const int* __restrict__ dst, int* __restrict__ hist)
{
    int e = blockIdx.x * blockDim.x + threadIdx.x;
    if (e >= N_EDGES) return;
    atomicAdd(&hist[dst[e]], 1);
}

// per-block partial sums of hist
__global__ __launch_bounds__(256) void scanA_kernel(
    const int* __restrict__ hist, int* __restrict__ bsum)
{
    __shared__ int sdata[256];
    int b = blockIdx.x;
    int t = threadIdx.x;
    int s = 0;
    int i0 = b * SCAN_CHUNK + t * 8;
#pragma unroll
    for (int q = 0; q < 8; ++q) {
        int i = i0 + q;
        if (i < N_NODES) s += hist[i];
    }
    sdata[t] = s;
    __syncthreads();
    for (int o = 1; o < 256; o <<= 1) {
        int tmp = (t >= o) ? sdata[t - o] : 0;
        __syncthreads();
        sdata[t] += tmp;
        __syncthreads();
    }
    if (t == 255) bsum[b] = sdata[255];
}

// single-block exclusive scan of block sums
__global__ __launch_bounds__(256) void scanB_kernel(
    const int* __restrict__ bsum, int* __restrict__ bbase)
{
    __shared__ int sdata[256];
    int t = threadIdx.x;
    int v = (t < SCAN_NB) ? bsum[t] : 0;
    sdata[t] = v;
    __syncthreads();
    for (int o = 1; o < 256; o <<= 1) {
        int tmp = (t >= o) ? sdata[t - o] : 0;
        __syncthreads();
        sdata[t] += tmp;
        __syncthreads();
    }
    if (t < SCAN_NB) bbase[t] = sdata[t] - v;   // exclusive
}

// per-block exclusive scan + write off[] and cursor[]
__global__ __launch_bounds__(256) void scanC_kernel(
    const int* __restrict__ hist, const int* __restrict__ bbase,
    int* __restrict__ off, int* __restrict__ cursor)
{
    __shared__ int sdata[256];
    int b = blockIdx.x;
    int t = threadIdx.x;
    int i0 = b * SCAN_CHUNK + t * 8;
    int local[8];
    int s = 0;
#pragma unroll
    for (int q = 0; q < 8; ++q) {
        int i = i0 + q;
        local[q] = (i < N_NODES) ? hist[i] : 0;
        s += local[q];
    }
    sdata[t] = s;
    __syncthreads();
    for (int o = 1; o < 256; o <<= 1) {
        int tmp = (t >= o) ? sdata[t - o] : 0;
        __syncthreads();
        sdata[t] += tmp;
        __syncthreads();
    }
    int run = bbase[b] + sdata[t] - s;   // exclusive prefix for first elem
#pragma unroll
    for (int q = 0; q < 8; ++q) {
        int i = i0 + q;
        if (i < N_NODES) {
            off[i] = run;
            cursor[i] = run;
            run += local[q];
            if (i == N_NODES - 1) off[N_NODES] = run;
        }
    }
}

__global__ __launch_bounds__(256) void scatter_sort_kernel(
    const int* __restrict__ src, const int* __restrict__ dst,
    int* __restrict__ cursor, int* __restrict__ sorted_src)
{
    int e = blockIdx.x * blockDim.x + threadIdx.x;
    if (e >= N_EDGES) return;
    int d = dst[e];
    int pos = atomicAdd(&cursor[d], 1);
    sorted_src[pos] = src[e];
}

// ---------------------------------------------------------------------------
// Gather: agg[i][j] = sum over edges of node i of h[src][j], G lanes per node.
// Lanes cooperatively load G edge indices (coalesced), then shfl-broadcast
// each and load one padded row per edge (G=16 -> exactly one 64B line).
// ---------------------------------------------------------------------------
template<int G>
__global__ __launch_bounds__(256) void gather_kernel(
    const int* __restrict__ off, const int* __restrict__ sorted_src,
    const float* __restrict__ h, float* __restrict__ agg)
{
    const int npb = 256 / G;
    int node = blockIdx.x * npb + threadIdx.x / G;
    int j = threadIdx.x % G;
    if (node >= N_NODES) return;
    int start = off[node];
    int end = off[node + 1];
    int gb = (threadIdx.x & 63) & ~(G - 1);   // group base lane within wave
    float acc = 0.0f;
    for (int base = start; base < end; base += G) {
        int e = base + j;
        int my = (e < end) ? sorted_src[e] : 0;
        int count = end - base;
        if (count > G) count = G;
        for (int t = 0; t < count; ++t) {
            int sb = __shfl(my, gb + t, 64);
            acc += h[(long)sb * G + j];
        }
    }
    agg[(long)node * G + j] = acc;
}

// specialization for G=1 (layer 1, scalar features)
__global__ __launch_bounds__(256) void gather1_kernel(
    const int* __restrict__ off, const int* __restrict__ sorted_src,
    const float* __restrict__ h, float* __restrict__ agg)
{
    int node = blockIdx.x * blockDim.x + threadIdx.x;
    if (node >= N_NODES) return;
    int start = off[node];
    int end = off[node + 1];
    float acc = 0.0f;
    for (int e = start; e < end; ++e)
        acc += h[sorted_src[e]];
    agg[node] = acc;
}

// ---------------------------------------------------------------------------
// Per-node transform: hout = relu(agg @ Wrel + brel + hin @ Wroot)
// SIN/SOUT are padded row strides.
// ---------------------------------------------------------------------------
template<int DIN, int SIN, int DOUT, int SOUT>
__global__ __launch_bounds__(256) void transform_kernel(
    const float* __restrict__ agg,
    const float* __restrict__ hin,
    const float* __restrict__ Wrel,
    const float* __restrict__ brel,
    const float* __restrict__ Wroot,
    float* __restrict__ hout)
{
    __shared__ float sWrel[DIN * DOUT];
    __shared__ float sWroot[DIN * DOUT];
    __shared__ float sbrel[DOUT];
    for (int t = threadIdx.x; t < DIN * DOUT; t += blockDim.x) {
        sWrel[t] = Wrel[t];
        sWroot[t] = Wroot[t];
    }
    for (int t = threadIdx.x; t < DOUT; t += blockDim.x) sbrel[t] = brel[t];
    __syncthreads();

    int i = blockIdx.x * blockDim.x + threadIdx.x;
    if (i >= N_NODES) return;

    float a[DIN], x[DIN];
#pragma unroll
    for (int k = 0; k < DIN; ++k) {
        a[k] = agg[(long)i * SIN + k];
        x[k] = hin[(long)i * SIN + k];
    }
#pragma unroll
    for (int o = 0; o < DOUT; ++o) {
        float v = sbrel[o];
#pragma unroll
        for (int k = 0; k < DIN; ++k)
            v += a[k] * sWrel[k * DOUT + o] + x[k] * sWroot[k * DOUT + o];
        hout[(long)i * SOUT + o] = fmaxf(v, 0.0f);
    }
}

// ---------------------------------------------------------------------------
// Fused layer-4 transform + 3-layer MLP (agg/h3 padded to stride 16).
// ---------------------------------------------------------------------------
__global__ __launch_bounds__(256) void layer4_mlp_kernel(
    const float* __restrict__ agg,
    const float* __restrict__ h3,
    const float* __restrict__ g4Wrel,   // [10][16]
    const float* __restrict__ g4brel,   // [16]
    const float* __restrict__ g4Wroot,  // [10][16]
    const float* __restrict__ fc1W,     // [16][32]
    const float* __restrict__ fc1b,     // [32]
    const float* __restrict__ fc2W,     // [32][16]
    const float* __restrict__ fc2b,     // [16]
    const float* __restrict__ fc3W,     // [16][16]
    const float* __restrict__ fc3b,     // [16]
    float* __restrict__ out)
{
    __shared__ float s[1680];
    float* sWrel  = s;            // 160
    float* sbrel  = s + 160;      // 16
    float* sWroot = s + 176;      // 160
    float* sfc1W  = s + 336;      // 512
    float* sfc1b  = s + 848;      // 32
    float* sfc2W  = s + 880;      // 512
    float* sfc2b  = s + 1392;     // 16
    float* sfc3W  = s + 1408;     // 256
    float* sfc3b  = s + 1664;     // 16

    for (int t = threadIdx.x; t < 160; t += blockDim.x) { sWrel[t] = g4Wrel[t]; sWroot[t] = g4Wroot[t]; }
    for (int t = threadIdx.x; t < 512; t += blockDim.x) { sfc1W[t] = fc1W[t]; sfc2W[t] = fc2W[t]; }
    for (int t = threadIdx.x; t < 256; t += blockDim.x) { sfc3W[t] = fc3W[t]; }
    for (int t = threadIdx.x; t < 32;  t += blockDim.x) { sfc1b[t] = fc1b[t]; }
    for (int t = threadIdx.x; t < 16;  t += blockDim.x) { sbrel[t] = g4brel[t]; sfc2b[t] = fc2b[t]; sfc3b[t] = fc3b[t]; }
    __syncthreads();

    int i = blockIdx.x * blockDim.x + threadIdx.x;
    if (i >= N_NODES) return;

    float a[10], x[10];
#pragma unroll
    for (int k = 0; k < 10; ++k) {
        a[k] = agg[(long)i * 16 + k];
        x[k] = h3[(long)i * 16 + k];
    }

    float h4[16];
#pragma unroll
    for (int o = 0; o < 16; ++o) {
        float v = sbrel[o];
#pragma unroll
        for (int k = 0; k < 10; ++k)
            v += a[k] * sWrel[k * 16 + o] + x[k] * sWroot[k * 16 + o];
        h4[o] = fmaxf(v, 0.0f);
    }

    float m1[32];
#pragma unroll
    for (int o = 0; o < 32; ++o) {
        float v = sfc1b[o];
#pragma unroll
        for (int k = 0; k < 16; ++k) v += h4[k] * sfc1W[k * 32 + o];
        m1[o] = fmaxf(v, 0.0f);
    }

    float m2[16];
#pragma unroll
    for (int o = 0; o < 16; ++o) {
        float v = sfc2b[o];
#pragma unroll
        for (int k = 0; k < 32; ++k) v += m1[k] * sfc2W[k * 16 + o];
        m2[o] = fmaxf(v, 0.0f);
    }

    float r[16];
#pragma unroll
    for (int o = 0; o < 16; ++o) {
        float v = sfc3b[o];
#pragma unroll
        for (int k = 0; k < 16; ++k) v += m2[k] * sfc3W[k * 16 + o];
        r[o] = v;
    }
    float4* op = (float4*)(out + (long)i * 16);
#pragma unroll
    for (int q = 0; q < 4; ++q)
        op[q] = make_float4(r[q * 4 + 0], r[q * 4 + 1], r[q * 4 + 2], r[q * 4 + 3]);
}

// ---------------------------------------------------------------------------
extern "C" void kernel_launch(void* const* d_in, const int* in_sizes, int n_in,
                              void* d_out, int out_size, void* d_ws, size_t ws_size,
                              hipStream_t stream) {
    const float* x        = (const float*)d_in[0];
    const int*   ei       = (const int*)d_in[1];
    const float* g1_Wrel  = (const float*)d_in[2];
    const float* g1_brel  = (const float*)d_in[3];
    const float* g1_Wroot = (const float*)d_in[4];
    const float* g2_Wrel  = (const float*)d_in[5];
    const float* g2_brel  = (const float*)d_in[6];
    const float* g2_Wroot = (const float*)d_in[7];
    const float* g3_Wrel  = (const float*)d_in[8];
    const float* g3_brel  = (const float*)d_in[9];
    const float* g3_Wroot = (const float*)d_in[10];
    const float* g4_Wrel  = (const float*)d_in[11];
    const float* g4_brel  = (const float*)d_in[12];
    const float* g4_Wroot = (const float*)d_in[13];
    const float* fc1_W    = (const float*)d_in[14];
    const float* fc1_b    = (const float*)d_in[15];
    const float* fc2_W    = (const float*)d_in[16];
    const float* fc2_b    = (const float*)d_in[17];
    const float* fc3_W    = (const float*)d_in[18];
    const float* fc3_b    = (const float*)d_in[19];
    float* out = (float*)d_out;

    const int* srcp = ei;
    const int* dstp = ei + N_EDGES;

    // ---- workspace layout (256B aligned chunks) ----
    char* p = (char*)d_ws;
    auto alloc = [&](size_t bytes) {
        char* r = p;
        p += (bytes + 255) & ~(size_t)255;
        return r;
    };
    int*   hist       = (int*)  alloc((size_t)N_NODES * 4);
    int*   off        = (int*)  alloc((size_t)(N_NODES + 1) * 4);
    int*   cursor     = (int*)  alloc((size_t)N_NODES * 4);
    int*   bsum       = (int*)  alloc(1024);
    int*   bbase      = (int*)  alloc(1024);
    int*   sorted_src = (int*)  alloc((size_t)N_EDGES * 4);          // 64 MB
    float* h1p        = (float*)alloc((size_t)N_NODES * 4 * 4);      //  8 MB
    float* h2p        = (float*)alloc((size_t)N_NODES * 8 * 4);      // 16 MB
    float* h3p        = (float*)alloc((size_t)N_NODES * 16 * 4);     // 32 MB
    float* agg        = (float*)alloc((size_t)N_NODES * 16 * 4);     // 32 MB

    const int TB = 256;
    const int edge_blocks = (N_EDGES + TB - 1) / TB;
    const int node_blocks = (N_NODES + TB - 1) / TB;

    // ---- build CSR (dst-sorted src list) ----
    hipMemsetAsync(hist, 0, (size_t)N_NODES * 4, stream);
    hist_kernel<<<edge_blocks, TB, 0, stream>>>(dstp, hist);
    scanA_kernel<<<SCAN_NB, TB, 0, stream>>>(hist, bsum);
    scanB_kernel<<<1, TB, 0, stream>>>(bsum, bbase);
    scanC_kernel<<<SCAN_NB, TB, 0, stream>>>(hist, bbase, off, cursor);
    scatter_sort_kernel<<<edge_blocks, TB, 0, stream>>>(srcp, dstp, cursor, sorted_src);

    // ---- layer 1: din=1 -> dout=4 (stride 4) ----
    gather1_kernel<<<node_blocks, TB, 0, stream>>>(off, sorted_src, x, agg);
    transform_kernel<1, 1, 4, 4><<<node_blocks, TB, 0, stream>>>(
        agg, x, g1_Wrel, g1_brel, g1_Wroot, h1p);

    // ---- layer 2: din=4 (stride 4) -> dout=7 (stride 8) ----
    gather_kernel<4><<<(N_NODES + 63) / 64, TB, 0, stream>>>(off, sorted_src, h1p, agg);
    transform_kernel<4, 4, 7, 8><<<node_blocks, TB, 0, stream>>>(
        agg, h1p, g2_Wrel, g2_brel, g2_Wroot, h2p);

    // ---- layer 3: din=7 (stride 8) -> dout=10 (stride 16) ----
    gather_kernel<8><<<(N_NODES + 31) / 32, TB, 0, stream>>>(off, sorted_src, h2p, agg);
    transform_kernel<7, 8, 10, 16><<<node_blocks, TB, 0, stream>>>(
        agg, h2p, g3_Wrel, g3_brel, g3_Wroot, h3p);

    // ---- layer 4 (din=10, stride 16) + MLP, fused ----
    gather_kernel<16><<<(N_NODES + 15) / 16, TB, 0, stream>>>(off, sorted_src, h3p, agg);
    layer4_mlp_kernel<<<node_blocks, TB, 0, stream>>>(
        agg, h3p, g4_Wrel, g4_brel, g4_Wroot,
        fc1_W, fc1_b, fc2_W, fc2_b, fc3_W, fc3_b, out);
}

// Round 3
// 2254.048 us; speedup vs baseline: 7.7701x; 1.1859x over previous
//
#include <hip/hip_runtime.h>

#define N_NODES 500000
#define N_EDGES 16000000
#define SCAN_CHUNK 2048
#define SCAN_NB ((N_NODES + SCAN_CHUNK - 1) / SCAN_CHUNK)   // 245

// bucketing: 1024 dst-nodes per bucket
#define BKT_BITS 10
#define BKT_SIZE (1 << BKT_BITS)
#define NBUCKET ((N_NODES + BKT_SIZE - 1) / BKT_SIZE)       // 489
#define BIN_EPT 32
#define BIN_CHUNK (256 * BIN_EPT)                            // 8192
#define BIN_NBLK ((N_EDGES + BIN_CHUNK - 1) / BIN_CHUNK)     // 1954

// ---------------------------------------------------------------------------
// per-node degree histogram
// ---------------------------------------------------------------------------
__global__ __launch_bounds__(256) void hist_kernel(
    const int* __restrict__ dst, int* __restrict__ hist)
{
    int e = blockIdx.x * blockDim.x + threadIdx.x;
    if (e >= N_EDGES) return;
    atomicAdd(&hist[dst[e]], 1);
}

// per-block partial sums of hist
__global__ __launch_bounds__(256) void scanA_kernel(
    const int* __restrict__ hist, int* __restrict__ bsum)
{
    __shared__ int sdata[256];
    int b = blockIdx.x;
    int t = threadIdx.x;
    int s = 0;
    int i0 = b * SCAN_CHUNK + t * 8;
#pragma unroll
    for (int q = 0; q < 8; ++q) {
        int i = i0 + q;
        if (i < N_NODES) s += hist[i];
    }
    sdata[t] = s;
    __syncthreads();
    for (int o = 1; o < 256; o <<= 1) {
        int tmp = (t >= o) ? sdata[t - o] : 0;
        __syncthreads();
        sdata[t] += tmp;
        __syncthreads();
    }
    if (t == 255) bsum[b] = sdata[255];
}

// single-block exclusive scan of block sums
__global__ __launch_bounds__(256) void scanB_kernel(
    const int* __restrict__ bsum, int* __restrict__ bbase)
{
    __shared__ int sdata[256];
    int t = threadIdx.x;
    int v = (t < SCAN_NB) ? bsum[t] : 0;
    sdata[t] = v;
    __syncthreads();
    for (int o = 1; o < 256; o <<= 1) {
        int tmp = (t >= o) ? sdata[t - o] : 0;
        __syncthreads();
        sdata[t] += tmp;
        __syncthreads();
    }
    if (t < SCAN_NB) bbase[t] = sdata[t] - v;   // exclusive
}

// per-block exclusive scan -> off[]
__global__ __launch_bounds__(256) void scanC_kernel(
    const int* __restrict__ hist, const int* __restrict__ bbase,
    int* __restrict__ off)
{
    __shared__ int sdata[256];
    int b = blockIdx.x;
    int t = threadIdx.x;
    int i0 = b * SCAN_CHUNK + t * 8;
    int local[8];
    int s = 0;
#pragma unroll
    for (int q = 0; q < 8; ++q) {
        int i = i0 + q;
        local[q] = (i < N_NODES) ? hist[i] : 0;
        s += local[q];
    }
    sdata[t] = s;
    __syncthreads();
    for (int o = 1; o < 256; o <<= 1) {
        int tmp = (t >= o) ? sdata[t - o] : 0;
        __syncthreads();
        sdata[t] += tmp;
        __syncthreads();
    }
    int run = bbase[b] + sdata[t] - s;   // exclusive prefix for first elem
#pragma unroll
    for (int q = 0; q < 8; ++q) {
        int i = i0 + q;
        if (i < N_NODES) {
            off[i] = run;
            run += local[q];
            if (i == N_NODES - 1) off[N_NODES] = run;
        }
    }
}

// bucket cursors: start of each bucket's region = off[b*1024]
__global__ __launch_bounds__(512) void init_bcur_kernel(
    const int* __restrict__ off, int* __restrict__ bcur)
{
    int b = threadIdx.x;
    if (b < NBUCKET) bcur[b] = off[b << BKT_BITS];
}

// ---------------------------------------------------------------------------
// Pass 1: bin edges into buckets of 1024 dst nodes. Block-aggregated LDS
// histogram -> one global atomicAdd per (block,bucket) -> clustered writes.
// pairs[pos] = (src << 10) | (dst & 1023)   (src < 2^19 -> fits 29 bits)
// ---------------------------------------------------------------------------
__global__ __launch_bounds__(256) void bin_kernel(
    const int* __restrict__ src, const int* __restrict__ dst,
    int* __restrict__ bcur, unsigned int* __restrict__ pairs)
{
    __shared__ int lh[NBUCKET];
    __shared__ int lbase[NBUCKET];
    int t = threadIdx.x;
    long e0 = (long)blockIdx.x * BIN_CHUNK;

    for (int b = t; b < NBUCKET; b += 256) lh[b] = 0;
    __syncthreads();

#pragma unroll
    for (int q = 0; q < BIN_EPT; ++q) {
        long e = e0 + q * 256 + t;
        if (e < N_EDGES) atomicAdd(&lh[dst[e] >> BKT_BITS], 1);
    }
    __syncthreads();

    for (int b = t; b < NBUCKET; b += 256) {
        int c = lh[b];
        lbase[b] = c ? atomicAdd(&bcur[b], c) : 0;
        lh[b] = 0;   // reuse as running counter
    }
    __syncthreads();

#pragma unroll
    for (int q = 0; q < BIN_EPT; ++q) {
        long e = e0 + q * 256 + t;
        if (e < N_EDGES) {
            int d = dst[e];
            int s = src[e];
            int b = d >> BKT_BITS;
            int r = atomicAdd(&lh[b], 1);
            pairs[lbase[b] + r] = ((unsigned int)s << BKT_BITS) | (unsigned int)(d & (BKT_SIZE - 1));
        }
    }
}

// ---------------------------------------------------------------------------
// Pass 2: one block per bucket. Per-node cursors in LDS; writes to
// sorted_src land in this bucket's contiguous ~128KB window.
// ---------------------------------------------------------------------------
__global__ __launch_bounds__(256) void bucket_sort_kernel(
    const int* __restrict__ off, const unsigned int* __restrict__ pairs,
    int* __restrict__ sorted_src)
{
    __shared__ int lcur[BKT_SIZE];
    int b = blockIdx.x;
    int t = threadIdx.x;
    int base_node = b << BKT_BITS;
    int end_node = base_node + BKT_SIZE;
    if (end_node > N_NODES) end_node = N_NODES;

    for (int i = t; i < BKT_SIZE; i += 256) {
        int node = base_node + i;
        lcur[i] = off[node <= N_NODES ? node : N_NODES];
    }
    __syncthreads();

    int start = off[base_node];
    int end = off[end_node];
    for (int e = start + t; e < end; e += 256) {
        unsigned int p = pairs[e];
        int s = (int)(p >> BKT_BITS);
        int low = (int)(p & (BKT_SIZE - 1));
        int pos = atomicAdd(&lcur[low], 1);
        sorted_src[pos] = s;
    }
}

// ---------------------------------------------------------------------------
// Gather: agg[i][j] = sum over edges of node i of h[src][j], G lanes per node.
// ---------------------------------------------------------------------------
template<int G>
__global__ __launch_bounds__(256) void gather_kernel(
    const int* __restrict__ off, const int* __restrict__ sorted_src,
    const float* __restrict__ h, float* __restrict__ agg)
{
    const int npb = 256 / G;
    int node = blockIdx.x * npb + threadIdx.x / G;
    int j = threadIdx.x % G;
    if (node >= N_NODES) return;
    int start = off[node];
    int end = off[node + 1];
    int gb = (threadIdx.x & 63) & ~(G - 1);   // group base lane within wave
    float acc = 0.0f;
    for (int base = start; base < end; base += G) {
        int e = base + j;
        int my = (e < end) ? sorted_src[e] : 0;
        int count = end - base;
        if (count > G) count = G;
        for (int t = 0; t < count; ++t) {
            int sb = __shfl(my, gb + t, 64);
            acc += h[(long)sb * G + j];
        }
    }
    agg[(long)node * G + j] = acc;
}

__global__ __launch_bounds__(256) void gather1_kernel(
    const int* __restrict__ off, const int* __restrict__ sorted_src,
    const float* __restrict__ h, float* __restrict__ agg)
{
    int node = blockIdx.x * blockDim.x + threadIdx.x;
    if (node >= N_NODES) return;
    int start = off[node];
    int end = off[node + 1];
    float acc = 0.0f;
    for (int e = start; e < end; ++e)
        acc += h[sorted_src[e]];
    agg[node] = acc;
}

// ---------------------------------------------------------------------------
// Per-node transform: hout = relu(agg @ Wrel + brel + hin @ Wroot)
// ---------------------------------------------------------------------------
template<int DIN, int SIN, int DOUT, int SOUT>
__global__ __launch_bounds__(256) void transform_kernel(
    const float* __restrict__ agg,
    const float* __restrict__ hin,
    const float* __restrict__ Wrel,
    const float* __restrict__ brel,
    const float* __restrict__ Wroot,
    float* __restrict__ hout)
{
    __shared__ float sWrel[DIN * DOUT];
    __shared__ float sWroot[DIN * DOUT];
    __shared__ float sbrel[DOUT];
    for (int t = threadIdx.x; t < DIN * DOUT; t += blockDim.x) {
        sWrel[t] = Wrel[t];
        sWroot[t] = Wroot[t];
    }
    for (int t = threadIdx.x; t < DOUT; t += blockDim.x) sbrel[t] = brel[t];
    __syncthreads();

    int i = blockIdx.x * blockDim.x + threadIdx.x;
    if (i >= N_NODES) return;

    float a[DIN], x[DIN];
#pragma unroll
    for (int k = 0; k < DIN; ++k) {
        a[k] = agg[(long)i * SIN + k];
        x[k] = hin[(long)i * SIN + k];
    }
#pragma unroll
    for (int o = 0; o < DOUT; ++o) {
        float v = sbrel[o];
#pragma unroll
        for (int k = 0; k < DIN; ++k)
            v += a[k] * sWrel[k * DOUT + o] + x[k] * sWroot[k * DOUT + o];
        hout[(long)i * SOUT + o] = fmaxf(v, 0.0f);
    }
}

// ---------------------------------------------------------------------------
// Fused layer-4 transform + 3-layer MLP (agg/h3 padded to stride 16).
// ---------------------------------------------------------------------------
__global__ __launch_bounds__(256) void layer4_mlp_kernel(
    const float* __restrict__ agg,
    const float* __restrict__ h3,
    const float* __restrict__ g4Wrel,
    const float* __restrict__ g4brel,
    const float* __restrict__ g4Wroot,
    const float* __restrict__ fc1W,
    const float* __restrict__ fc1b,
    const float* __restrict__ fc2W,
    const float* __restrict__ fc2b,
    const float* __restrict__ fc3W,
    const float* __restrict__ fc3b,
    float* __restrict__ out)
{
    __shared__ float s[1680];
    float* sWrel  = s;            // 160
    float* sbrel  = s + 160;      // 16
    float* sWroot = s + 176;      // 160
    float* sfc1W  = s + 336;      // 512
    float* sfc1b  = s + 848;      // 32
    float* sfc2W  = s + 880;      // 512
    float* sfc2b  = s + 1392;     // 16
    float* sfc3W  = s + 1408;     // 256
    float* sfc3b  = s + 1664;     // 16

    for (int t = threadIdx.x; t < 160; t += blockDim.x) { sWrel[t] = g4Wrel[t]; sWroot[t] = g4Wroot[t]; }
    for (int t = threadIdx.x; t < 512; t += blockDim.x) { sfc1W[t] = fc1W[t]; sfc2W[t] = fc2W[t]; }
    for (int t = threadIdx.x; t < 256; t += blockDim.x) { sfc3W[t] = fc3W[t]; }
    for (int t = threadIdx.x; t < 32;  t += blockDim.x) { sfc1b[t] = fc1b[t]; }
    for (int t = threadIdx.x; t < 16;  t += blockDim.x) { sbrel[t] = g4brel[t]; sfc2b[t] = fc2b[t]; sfc3b[t] = fc3b[t]; }
    __syncthreads();

    int i = blockIdx.x * blockDim.x + threadIdx.x;
    if (i >= N_NODES) return;

    float a[10], x[10];
#pragma unroll
    for (int k = 0; k < 10; ++k) {
        a[k] = agg[(long)i * 16 + k];
        x[k] = h3[(long)i * 16 + k];
    }

    float h4[16];
#pragma unroll
    for (int o = 0; o < 16; ++o) {
        float v = sbrel[o];
#pragma unroll
        for (int k = 0; k < 10; ++k)
            v += a[k] * sWrel[k * 16 + o] + x[k] * sWroot[k * 16 + o];
        h4[o] = fmaxf(v, 0.0f);
    }

    float m1[32];
#pragma unroll
    for (int o = 0; o < 32; ++o) {
        float v = sfc1b[o];
#pragma unroll
        for (int k = 0; k < 16; ++k) v += h4[k] * sfc1W[k * 32 + o];
        m1[o] = fmaxf(v, 0.0f);
    }

    float m2[16];
#pragma unroll
    for (int o = 0; o < 16; ++o) {
        float v = sfc2b[o];
#pragma unroll
        for (int k = 0; k < 32; ++k) v += m1[k] * sfc2W[k * 16 + o];
        m2[o] = fmaxf(v, 0.0f);
    }

    float r[16];
#pragma unroll
    for (int o = 0; o < 16; ++o) {
        float v = sfc3b[o];
#pragma unroll
        for (int k = 0; k < 16; ++k) v += m2[k] * sfc3W[k * 16 + o];
        r[o] = v;
    }
    float4* op = (float4*)(out + (long)i * 16);
#pragma unroll
    for (int q = 0; q < 4; ++q)
        op[q] = make_float4(r[q * 4 + 0], r[q * 4 + 1], r[q * 4 + 2], r[q * 4 + 3]);
}

// ---------------------------------------------------------------------------
extern "C" void kernel_launch(void* const* d_in, const int* in_sizes, int n_in,
                              void* d_out, int out_size, void* d_ws, size_t ws_size,
                              hipStream_t stream) {
    const float* x        = (const float*)d_in[0];
    const int*   ei       = (const int*)d_in[1];
    const float* g1_Wrel  = (const float*)d_in[2];
    const float* g1_brel  = (const float*)d_in[3];
    const float* g1_Wroot = (const float*)d_in[4];
    const float* g2_Wrel  = (const float*)d_in[5];
    const float* g2_brel  = (const float*)d_in[6];
    const float* g2_Wroot = (const float*)d_in[7];
    const float* g3_Wrel  = (const float*)d_in[8];
    const float* g3_brel  = (const float*)d_in[9];
    const float* g3_Wroot = (const float*)d_in[10];
    const float* g4_Wrel  = (const float*)d_in[11];
    const float* g4_brel  = (const float*)d_in[12];
    const float* g4_Wroot = (const float*)d_in[13];
    const float* fc1_W    = (const float*)d_in[14];
    const float* fc1_b    = (const float*)d_in[15];
    const float* fc2_W    = (const float*)d_in[16];
    const float* fc2_b    = (const float*)d_in[17];
    const float* fc3_W    = (const float*)d_in[18];
    const float* fc3_b    = (const float*)d_in[19];
    float* out = (float*)d_out;

    const int* srcp = ei;
    const int* dstp = ei + N_EDGES;

    // ---- workspace layout (256B aligned) ----
    char* p = (char*)d_ws;
    auto alloc = [&](size_t bytes) {
        char* r = p;
        p += (bytes + 255) & ~(size_t)255;
        return r;
    };
    int*   hist       = (int*)  alloc((size_t)N_NODES * 4);          //  2 MB
    int*   off        = (int*)  alloc((size_t)(N_NODES + 1) * 4);    //  2 MB
    int*   bcur       = (int*)  alloc((size_t)NBUCKET * 4);
    int*   bsum       = (int*)  alloc(1024);
    int*   bbase      = (int*)  alloc(1024);
    float* h1p        = (float*)alloc((size_t)N_NODES * 4 * 4);      //  8 MB
    float* h2p        = (float*)alloc((size_t)N_NODES * 8 * 4);      // 16 MB
    float* h3p        = (float*)alloc((size_t)N_NODES * 16 * 4);     // 32 MB
    float* agg        = (float*)alloc((size_t)N_NODES * 16 * 4);     // 32 MB
    int*   sorted_src = (int*)  alloc((size_t)N_EDGES * 4);          // 64 MB
    // pairs (64 MB) is transient, dead before any h/agg write: alias h1p.
    unsigned int* pairs = (unsigned int*)h1p;

    const int TB = 256;
    const int edge_blocks = (N_EDGES + TB - 1) / TB;
    const int node_blocks = (N_NODES + TB - 1) / TB;

    // ---- build CSR (binned counting sort by dst) ----
    hipMemsetAsync(hist, 0, (size_t)N_NODES * 4, stream);
    hist_kernel<<<edge_blocks, TB, 0, stream>>>(dstp, hist);
    scanA_kernel<<<SCAN_NB, TB, 0, stream>>>(hist, bsum);
    scanB_kernel<<<1, TB, 0, stream>>>(bsum, bbase);
    scanC_kernel<<<SCAN_NB, TB, 0, stream>>>(hist, bbase, off);
    init_bcur_kernel<<<1, 512, 0, stream>>>(off, bcur);
    bin_kernel<<<BIN_NBLK, TB, 0, stream>>>(srcp, dstp, bcur, pairs);
    bucket_sort_kernel<<<NBUCKET, TB, 0, stream>>>(off, pairs, sorted_src);

    // ---- layer 1: din=1 -> dout=4 (stride 4) ----
    gather1_kernel<<<node_blocks, TB, 0, stream>>>(off, sorted_src, x, agg);
    transform_kernel<1, 1, 4, 4><<<node_blocks, TB, 0, stream>>>(
        agg, x, g1_Wrel, g1_brel, g1_Wroot, h1p);

    // ---- layer 2: din=4 (stride 4) -> dout=7 (stride 8) ----
    gather_kernel<4><<<(N_NODES + 63) / 64, TB, 0, stream>>>(off, sorted_src, h1p, agg);
    transform_kernel<4, 4, 7, 8><<<node_blocks, TB, 0, stream>>>(
        agg, h1p, g2_Wrel, g2_brel, g2_Wroot, h2p);

    // ---- layer 3: din=7 (stride 8) -> dout=10 (stride 16) ----
    gather_kernel<8><<<(N_NODES + 31) / 32, TB, 0, stream>>>(off, sorted_src, h2p, agg);
    transform_kernel<7, 8, 10, 16><<<node_blocks, TB, 0, stream>>>(
        agg, h2p, g3_Wrel, g3_brel, g3_Wroot, h3p);

    // ---- layer 4 (din=10, stride 16) + MLP, fused ----
    gather_kernel<16><<<(N_NODES + 15) / 16, TB, 0, stream>>>(off, sorted_src, h3p, agg);
    layer4_mlp_kernel<<<node_blocks, TB, 0, stream>>>(
        agg, h3p, g4_Wrel, g4_brel, g4_Wroot,
        fc1_W, fc1_b, fc2_W, fc2_b, fc3_W, fc3_b, out);
}

// Round 4
// 1726.608 us; speedup vs baseline: 10.1437x; 1.3055x over previous
//
#include <hip/hip_runtime.h>

#define N_NODES 500000
#define N_EDGES 16000000

// bucketing: 1024 dst-nodes per bucket
#define BKT_BITS 10
#define BKT_SIZE (1 << BKT_BITS)
#define NBUCKET ((N_NODES + BKT_SIZE - 1) / BKT_SIZE)       // 489
#define BIN_EPT 32
#define BIN_CHUNK (256 * BIN_EPT)                            // 8192
#define BIN_NBLK ((N_EDGES + BIN_CHUNK - 1) / BIN_CHUNK)     // 1954

// ---------------------------------------------------------------------------
// Bucket histogram (489 bins): per-block LDS aggregation -> <=489 global
// atomics per block onto a 2KB hot counter array (L2-resident).
// ---------------------------------------------------------------------------
__global__ __launch_bounds__(256) void bucket_hist_kernel(
    const int* __restrict__ dst, int* __restrict__ bhist)
{
    __shared__ int lh[NBUCKET];
    int t = threadIdx.x;
    long e0 = (long)blockIdx.x * BIN_CHUNK;
    for (int b = t; b < NBUCKET; b += 256) lh[b] = 0;
    __syncthreads();
#pragma unroll
    for (int q = 0; q < BIN_EPT; ++q) {
        long e = e0 + q * 256 + t;
        if (e < N_EDGES) atomicAdd(&lh[dst[e] >> BKT_BITS], 1);
    }
    __syncthreads();
    for (int b = t; b < NBUCKET; b += 256) {
        int c = lh[b];
        if (c) atomicAdd(&bhist[b], c);
    }
}

// single-block exclusive scan of 489 bucket totals -> bbase[0..NBUCKET], bcur
__global__ __launch_bounds__(512) void bucket_scan_kernel(
    const int* __restrict__ bhist, int* __restrict__ bbase, int* __restrict__ bcur)
{
    __shared__ int sdata[512];
    int t = threadIdx.x;
    int v = (t < NBUCKET) ? bhist[t] : 0;
    sdata[t] = v;
    __syncthreads();
    for (int o = 1; o < 512; o <<= 1) {
        int tmp = (t >= o) ? sdata[t - o] : 0;
        __syncthreads();
        sdata[t] += tmp;
        __syncthreads();
    }
    if (t < NBUCKET) {
        int excl = sdata[t] - v;
        bbase[t] = excl;
        bcur[t] = excl;
        if (t == NBUCKET - 1) bbase[NBUCKET] = sdata[t];
    }
}

// ---------------------------------------------------------------------------
// Pass 1: bin edges into buckets. Block-aggregated LDS histogram -> one
// global atomicAdd per (block,bucket) to reserve slots -> clustered writes.
// pairs[pos] = (src << 10) | (dst & 1023)
// ---------------------------------------------------------------------------
__global__ __launch_bounds__(256) void bin_kernel(
    const int* __restrict__ src, const int* __restrict__ dst,
    int* __restrict__ bcur, unsigned int* __restrict__ pairs)
{
    __shared__ int lh[NBUCKET];
    __shared__ int lbase[NBUCKET];
    int t = threadIdx.x;
    long e0 = (long)blockIdx.x * BIN_CHUNK;

    for (int b = t; b < NBUCKET; b += 256) lh[b] = 0;
    __syncthreads();

#pragma unroll
    for (int q = 0; q < BIN_EPT; ++q) {
        long e = e0 + q * 256 + t;
        if (e < N_EDGES) atomicAdd(&lh[dst[e] >> BKT_BITS], 1);
    }
    __syncthreads();

    for (int b = t; b < NBUCKET; b += 256) {
        int c = lh[b];
        lbase[b] = c ? atomicAdd(&bcur[b], c) : 0;
        lh[b] = 0;   // reuse as running counter
    }
    __syncthreads();

#pragma unroll
    for (int q = 0; q < BIN_EPT; ++q) {
        long e = e0 + q * 256 + t;
        if (e < N_EDGES) {
            int d = dst[e];
            int s = src[e];
            int b = d >> BKT_BITS;
            int r = atomicAdd(&lh[b], 1);
            pairs[lbase[b] + r] = ((unsigned int)s << BKT_BITS) | (unsigned int)(d & (BKT_SIZE - 1));
        }
    }
}

// ---------------------------------------------------------------------------
// Pass 2: one block per bucket. LDS histogram of low bits + LDS scan builds
// off[] for this bucket (coalesced write) AND the per-node cursors; then
// place edges: writes land in this bucket's contiguous ~130KB window.
// ---------------------------------------------------------------------------
__global__ __launch_bounds__(256) void bucket_sort_kernel(
    const int* __restrict__ bbase, const unsigned int* __restrict__ pairs,
    int* __restrict__ off, int* __restrict__ sorted_src)
{
    __shared__ int lh[BKT_SIZE];     // histogram -> cursors
    __shared__ int sdata[256];
    int b = blockIdx.x;
    int t = threadIdx.x;
    int base_node = b << BKT_BITS;
    int start = bbase[b];
    int end = bbase[b + 1];

    for (int i = t; i < BKT_SIZE; i += 256) lh[i] = 0;
    __syncthreads();

    for (int e = start + t; e < end; e += 256)
        atomicAdd(&lh[pairs[e] & (BKT_SIZE - 1)], 1);
    __syncthreads();

    // exclusive scan of lh[1024]: 4 elems per thread
    int i0 = t * 4;
    int c0 = lh[i0], c1 = lh[i0 + 1], c2 = lh[i0 + 2], c3 = lh[i0 + 3];
    int s = c0 + c1 + c2 + c3;
    sdata[t] = s;
    __syncthreads();
    for (int o = 1; o < 256; o <<= 1) {
        int tmp = (t >= o) ? sdata[t - o] : 0;
        __syncthreads();
        sdata[t] += tmp;
        __syncthreads();
    }
    int run = start + sdata[t] - s;   // global exclusive prefix for elem i0
    int vals[4] = {c0, c1, c2, c3};
#pragma unroll
    for (int q = 0; q < 4; ++q) {
        int node = base_node + i0 + q;
        if (node < N_NODES) {
            off[node] = run;
            if (node == N_NODES - 1) off[N_NODES] = run + vals[q];
        }
        lh[i0 + q] = run;             // cursor
        run += vals[q];
    }
    __syncthreads();

    // place edges via LDS cursors
    for (int e = start + t; e < end; e += 256) {
        unsigned int p = pairs[e];
        int pos = atomicAdd(&lh[p & (BKT_SIZE - 1)], 1);
        sorted_src[pos] = (int)(p >> BKT_BITS);
    }
}

// ---------------------------------------------------------------------------
// Gather: agg[i][j] = sum over edges of node i of h[src][j], G lanes per node.
// ---------------------------------------------------------------------------
template<int G>
__global__ __launch_bounds__(256) void gather_kernel(
    const int* __restrict__ off, const int* __restrict__ sorted_src,
    const float* __restrict__ h, float* __restrict__ agg)
{
    const int npb = 256 / G;
    int node = blockIdx.x * npb + threadIdx.x / G;
    int j = threadIdx.x % G;
    if (node >= N_NODES) return;
    int start = off[node];
    int end = off[node + 1];
    int gb = (threadIdx.x & 63) & ~(G - 1);   // group base lane within wave
    float acc = 0.0f;
    for (int base = start; base < end; base += G) {
        int e = base + j;
        int my = (e < end) ? sorted_src[e] : 0;
        int count = end - base;
        if (count > G) count = G;
        for (int t = 0; t < count; ++t) {
            int sb = __shfl(my, gb + t, 64);
            acc += h[(long)sb * G + j];
        }
    }
    agg[(long)node * G + j] = acc;
}

__global__ __launch_bounds__(256) void gather1_kernel(
    const int* __restrict__ off, const int* __restrict__ sorted_src,
    const float* __restrict__ h, float* __restrict__ agg)
{
    int node = blockIdx.x * blockDim.x + threadIdx.x;
    if (node >= N_NODES) return;
    int start = off[node];
    int end = off[node + 1];
    float acc = 0.0f;
    for (int e = start; e < end; ++e)
        acc += h[sorted_src[e]];
    agg[node] = acc;
}

// ---------------------------------------------------------------------------
// Per-node transform: hout = relu(agg @ Wrel + brel + hin @ Wroot)
// ---------------------------------------------------------------------------
template<int DIN, int SIN, int DOUT, int SOUT>
__global__ __launch_bounds__(256) void transform_kernel(
    const float* __restrict__ agg,
    const float* __restrict__ hin,
    const float* __restrict__ Wrel,
    const float* __restrict__ brel,
    const float* __restrict__ Wroot,
    float* __restrict__ hout)
{
    __shared__ float sWrel[DIN * DOUT];
    __shared__ float sWroot[DIN * DOUT];
    __shared__ float sbrel[DOUT];
    for (int t = threadIdx.x; t < DIN * DOUT; t += blockDim.x) {
        sWrel[t] = Wrel[t];
        sWroot[t] = Wroot[t];
    }
    for (int t = threadIdx.x; t < DOUT; t += blockDim.x) sbrel[t] = brel[t];
    __syncthreads();

    int i = blockIdx.x * blockDim.x + threadIdx.x;
    if (i >= N_NODES) return;

    float a[DIN], x[DIN];
#pragma unroll
    for (int k = 0; k < DIN; ++k) {
        a[k] = agg[(long)i * SIN + k];
        x[k] = hin[(long)i * SIN + k];
    }
#pragma unroll
    for (int o = 0; o < DOUT; ++o) {
        float v = sbrel[o];
#pragma unroll
        for (int k = 0; k < DIN; ++k)
            v += a[k] * sWrel[k * DOUT + o] + x[k] * sWroot[k * DOUT + o];
        hout[(long)i * SOUT + o] = fmaxf(v, 0.0f);
    }
}

// ---------------------------------------------------------------------------
// Fused layer-4 transform + 3-layer MLP (agg/h3 padded to stride 16).
// ---------------------------------------------------------------------------
__global__ __launch_bounds__(256) void layer4_mlp_kernel(
    const float* __restrict__ agg,
    const float* __restrict__ h3,
    const float* __restrict__ g4Wrel,
    const float* __restrict__ g4brel,
    const float* __restrict__ g4Wroot,
    const float* __restrict__ fc1W,
    const float* __restrict__ fc1b,
    const float* __restrict__ fc2W,
    const float* __restrict__ fc2b,
    const float* __restrict__ fc3W,
    const float* __restrict__ fc3b,
    float* __restrict__ out)
{
    __shared__ float s[1680];
    float* sWrel  = s;            // 160
    float* sbrel  = s + 160;      // 16
    float* sWroot = s + 176;      // 160
    float* sfc1W  = s + 336;      // 512
    float* sfc1b  = s + 848;      // 32
    float* sfc2W  = s + 880;      // 512
    float* sfc2b  = s + 1392;     // 16
    float* sfc3W  = s + 1408;     // 256
    float* sfc3b  = s + 1664;     // 16

    for (int t = threadIdx.x; t < 160; t += blockDim.x) { sWrel[t] = g4Wrel[t]; sWroot[t] = g4Wroot[t]; }
    for (int t = threadIdx.x; t < 512; t += blockDim.x) { sfc1W[t] = fc1W[t]; sfc2W[t] = fc2W[t]; }
    for (int t = threadIdx.x; t < 256; t += blockDim.x) { sfc3W[t] = fc3W[t]; }
    for (int t = threadIdx.x; t < 32;  t += blockDim.x) { sfc1b[t] = fc1b[t]; }
    for (int t = threadIdx.x; t < 16;  t += blockDim.x) { sbrel[t] = g4brel[t]; sfc2b[t] = fc2b[t]; sfc3b[t] = fc3b[t]; }
    __syncthreads();

    int i = blockIdx.x * blockDim.x + threadIdx.x;
    if (i >= N_NODES) return;

    float a[10], x[10];
#pragma unroll
    for (int k = 0; k < 10; ++k) {
        a[k] = agg[(long)i * 16 + k];
        x[k] = h3[(long)i * 16 + k];
    }

    float h4[16];
#pragma unroll
    for (int o = 0; o < 16; ++o) {
        float v = sbrel[o];
#pragma unroll
        for (int k = 0; k < 10; ++k)
            v += a[k] * sWrel[k * 16 + o] + x[k] * sWroot[k * 16 + o];
        h4[o] = fmaxf(v, 0.0f);
    }

    float m1[32];
#pragma unroll
    for (int o = 0; o < 32; ++o) {
        float v = sfc1b[o];
#pragma unroll
        for (int k = 0; k < 16; ++k) v += h4[k] * sfc1W[k * 32 + o];
        m1[o] = fmaxf(v, 0.0f);
    }

    float m2[16];
#pragma unroll
    for (int o = 0; o < 16; ++o) {
        float v = sfc2b[o];
#pragma unroll
        for (int k = 0; k < 32; ++k) v += m1[k] * sfc2W[k * 16 + o];
        m2[o] = fmaxf(v, 0.0f);
    }

    float r[16];
#pragma unroll
    for (int o = 0; o < 16; ++o) {
        float v = sfc3b[o];
#pragma unroll
        for (int k = 0; k < 16; ++k) v += m2[k] * sfc3W[k * 16 + o];
        r[o] = v;
    }
    float4* op = (float4*)(out + (long)i * 16);
#pragma unroll
    for (int q = 0; q < 4; ++q)
        op[q] = make_float4(r[q * 4 + 0], r[q * 4 + 1], r[q * 4 + 2], r[q * 4 + 3]);
}

// ---------------------------------------------------------------------------
extern "C" void kernel_launch(void* const* d_in, const int* in_sizes, int n_in,
                              void* d_out, int out_size, void* d_ws, size_t ws_size,
                              hipStream_t stream) {
    const float* x        = (const float*)d_in[0];
    const int*   ei       = (const int*)d_in[1];
    const float* g1_Wrel  = (const float*)d_in[2];
    const float* g1_brel  = (const float*)d_in[3];
    const float* g1_Wroot = (const float*)d_in[4];
    const float* g2_Wrel  = (const float*)d_in[5];
    const float* g2_brel  = (const float*)d_in[6];
    const float* g2_Wroot = (const float*)d_in[7];
    const float* g3_Wrel  = (const float*)d_in[8];
    const float* g3_brel  = (const float*)d_in[9];
    const float* g3_Wroot = (const float*)d_in[10];
    const float* g4_Wrel  = (const float*)d_in[11];
    const float* g4_brel  = (const float*)d_in[12];
    const float* g4_Wroot = (const float*)d_in[13];
    const float* fc1_W    = (const float*)d_in[14];
    const float* fc1_b    = (const float*)d_in[15];
    const float* fc2_W    = (const float*)d_in[16];
    const float* fc2_b    = (const float*)d_in[17];
    const float* fc3_W    = (const float*)d_in[18];
    const float* fc3_b    = (const float*)d_in[19];
    float* out = (float*)d_out;

    const int* srcp = ei;
    const int* dstp = ei + N_EDGES;

    // ---- workspace layout (256B aligned) ----
    char* p = (char*)d_ws;
    auto alloc = [&](size_t bytes) {
        char* r = p;
        p += (bytes + 255) & ~(size_t)255;
        return r;
    };
    int*   off        = (int*)  alloc((size_t)(N_NODES + 1) * 4);    //  2 MB
    int*   bhist      = (int*)  alloc((size_t)NBUCKET * 4);
    int*   bbase      = (int*)  alloc((size_t)(NBUCKET + 1) * 4);
    int*   bcur       = (int*)  alloc((size_t)NBUCKET * 4);
    float* h1p        = (float*)alloc((size_t)N_NODES * 4 * 4);      //  8 MB
    float* h2p        = (float*)alloc((size_t)N_NODES * 8 * 4);      // 16 MB
    float* h3p        = (float*)alloc((size_t)N_NODES * 16 * 4);     // 32 MB
    float* agg        = (float*)alloc((size_t)N_NODES * 16 * 4);     // 32 MB
    int*   sorted_src = (int*)  alloc((size_t)N_EDGES * 4);          // 64 MB
    // pairs (64 MB) is transient, dead before any h/agg write: alias h1p
    // (spans h1p+h2p+h3p+part of agg; all consumed by bucket_sort first).
    unsigned int* pairs = (unsigned int*)h1p;

    const int TB = 256;
    const int node_blocks = (N_NODES + TB - 1) / TB;

    // ---- build CSR (binned counting sort by dst; no per-node histogram) ----
    hipMemsetAsync(bhist, 0, (size_t)NBUCKET * 4, stream);
    bucket_hist_kernel<<<BIN_NBLK, TB, 0, stream>>>(dstp, bhist);
    bucket_scan_kernel<<<1, 512, 0, stream>>>(bhist, bbase, bcur);
    bin_kernel<<<BIN_NBLK, TB, 0, stream>>>(srcp, dstp, bcur, pairs);
    bucket_sort_kernel<<<NBUCKET, TB, 0, stream>>>(bbase, pairs, off, sorted_src);

    // ---- layer 1: din=1 -> dout=4 (stride 4) ----
    gather1_kernel<<<node_blocks, TB, 0, stream>>>(off, sorted_src, x, agg);
    transform_kernel<1, 1, 4, 4><<<node_blocks, TB, 0, stream>>>(
        agg, x, g1_Wrel, g1_brel, g1_Wroot, h1p);

    // ---- layer 2: din=4 (stride 4) -> dout=7 (stride 8) ----
    gather_kernel<4><<<(N_NODES + 63) / 64, TB, 0, stream>>>(off, sorted_src, h1p, agg);
    transform_kernel<4, 4, 7, 8><<<node_blocks, TB, 0, stream>>>(
        agg, h1p, g2_Wrel, g2_brel, g2_Wroot, h2p);

    // ---- layer 3: din=7 (stride 8) -> dout=10 (stride 16) ----
    gather_kernel<8><<<(N_NODES + 31) / 32, TB, 0, stream>>>(off, sorted_src, h2p, agg);
    transform_kernel<7, 8, 10, 16><<<node_blocks, TB, 0, stream>>>(
        agg, h2p, g3_Wrel, g3_brel, g3_Wroot, h3p);

    // ---- layer 4 (din=10, stride 16) + MLP, fused ----
    gather_kernel<16><<<(N_NODES + 15) / 16, TB, 0, stream>>>(off, sorted_src, h3p, agg);
    layer4_mlp_kernel<<<node_blocks, TB, 0, stream>>>(
        agg, h3p, g4_Wrel, g4_brel, g4_Wroot,
        fc1_W, fc1_b, fc2_W, fc2_b, fc3_W, fc3_b, out);
}

// Round 5
// 1430.524 us; speedup vs baseline: 12.2432x; 1.2070x over previous
//
#include <hip/hip_runtime.h>

#define N_NODES 500000
#define N_EDGES 16000000

// bucketing: 1024 dst-nodes per bucket
#define BKT_BITS 10
#define BKT_SIZE (1 << BKT_BITS)
#define NBUCKET ((N_NODES + BKT_SIZE - 1) / BKT_SIZE)       // 489
#define BIN_EPT 128
#define BIN_CHUNK (256 * BIN_EPT)                            // 32768 edges
#define BIN_NBLK ((N_EDGES + BIN_CHUNK - 1) / BIN_CHUNK)     // 489
#define BIN_VQ (BIN_EPT / 4)                                 // 32 int4/thread
#define NV4 (N_EDGES / 4)                                    // 4M int4

// ---------------------------------------------------------------------------
// Bucket histogram (489 bins): per-block LDS aggregation, int4 edge reads.
// ---------------------------------------------------------------------------
__global__ __launch_bounds__(256) void bucket_hist_kernel(
    const int* __restrict__ dst, int* __restrict__ bhist)
{
    __shared__ int lh[NBUCKET];
    const int4* dst4 = (const int4*)dst;
    int t = threadIdx.x;
    long v0 = (long)blockIdx.x * (BIN_CHUNK / 4);
    for (int b = t; b < NBUCKET; b += 256) lh[b] = 0;
    __syncthreads();
#pragma unroll
    for (int q = 0; q < BIN_VQ; ++q) {
        long v = v0 + q * 256 + t;
        if (v < NV4) {
            int4 d = dst4[v];
            atomicAdd(&lh[d.x >> BKT_BITS], 1);
            atomicAdd(&lh[d.y >> BKT_BITS], 1);
            atomicAdd(&lh[d.z >> BKT_BITS], 1);
            atomicAdd(&lh[d.w >> BKT_BITS], 1);
        }
    }
    __syncthreads();
    for (int b = t; b < NBUCKET; b += 256) {
        int c = lh[b];
        if (c) atomicAdd(&bhist[b], c);
    }
}

// single-block exclusive scan of 489 bucket totals -> bbase[0..NBUCKET], bcur
__global__ __launch_bounds__(512) void bucket_scan_kernel(
    const int* __restrict__ bhist, int* __restrict__ bbase, int* __restrict__ bcur)
{
    __shared__ int sdata[512];
    int t = threadIdx.x;
    int v = (t < NBUCKET) ? bhist[t] : 0;
    sdata[t] = v;
    __syncthreads();
    for (int o = 1; o < 512; o <<= 1) {
        int tmp = (t >= o) ? sdata[t - o] : 0;
        __syncthreads();
        sdata[t] += tmp;
        __syncthreads();
    }
    if (t < NBUCKET) {
        int excl = sdata[t] - v;
        bbase[t] = excl;
        bcur[t] = excl;
        if (t == NBUCKET - 1) bbase[NBUCKET] = sdata[t];
    }
}

// ---------------------------------------------------------------------------
// Pass 1: bin edges into buckets. LDS histogram -> one global atomicAdd per
// (block,bucket) -> long clustered runs (~268B avg). int4 edge reads.
// pairs[pos] = (src << 10) | (dst & 1023)
// ---------------------------------------------------------------------------
__global__ __launch_bounds__(256) void bin_kernel(
    const int* __restrict__ src, const int* __restrict__ dst,
    int* __restrict__ bcur, unsigned int* __restrict__ pairs)
{
    __shared__ int lh[NBUCKET];
    __shared__ int lbase[NBUCKET];
    const int4* dst4 = (const int4*)dst;
    const int4* src4 = (const int4*)src;
    int t = threadIdx.x;
    long v0 = (long)blockIdx.x * (BIN_CHUNK / 4);

    for (int b = t; b < NBUCKET; b += 256) lh[b] = 0;
    __syncthreads();

#pragma unroll
    for (int q = 0; q < BIN_VQ; ++q) {
        long v = v0 + q * 256 + t;
        if (v < NV4) {
            int4 d = dst4[v];
            atomicAdd(&lh[d.x >> BKT_BITS], 1);
            atomicAdd(&lh[d.y >> BKT_BITS], 1);
            atomicAdd(&lh[d.z >> BKT_BITS], 1);
            atomicAdd(&lh[d.w >> BKT_BITS], 1);
        }
    }
    __syncthreads();

    for (int b = t; b < NBUCKET; b += 256) {
        int c = lh[b];
        lbase[b] = c ? atomicAdd(&bcur[b], c) : 0;
        lh[b] = 0;   // reuse as running counter
    }
    __syncthreads();

#pragma unroll
    for (int q = 0; q < BIN_VQ; ++q) {
        long v = v0 + q * 256 + t;
        if (v < NV4) {
            int4 d = dst4[v];
            int4 s = src4[v];
            {
                int b = d.x >> BKT_BITS;
                int r = atomicAdd(&lh[b], 1);
                pairs[lbase[b] + r] = ((unsigned int)s.x << BKT_BITS) | (unsigned int)(d.x & (BKT_SIZE - 1));
            }
            {
                int b = d.y >> BKT_BITS;
                int r = atomicAdd(&lh[b], 1);
                pairs[lbase[b] + r] = ((unsigned int)s.y << BKT_BITS) | (unsigned int)(d.y & (BKT_SIZE - 1));
            }
            {
                int b = d.z >> BKT_BITS;
                int r = atomicAdd(&lh[b], 1);
                pairs[lbase[b] + r] = ((unsigned int)s.z << BKT_BITS) | (unsigned int)(d.z & (BKT_SIZE - 1));
            }
            {
                int b = d.w >> BKT_BITS;
                int r = atomicAdd(&lh[b], 1);
                pairs[lbase[b] + r] = ((unsigned int)s.w << BKT_BITS) | (unsigned int)(d.w & (BKT_SIZE - 1));
            }
        }
    }
}

// ---------------------------------------------------------------------------
// Pass 2: one block per bucket. LDS histogram + scan builds off[] and
// per-node cursors; places edges into the bucket's contiguous window.
// FUSED: also accumulates layer-1 aggregation agg1[i] = sum x[src] in LDS.
// ---------------------------------------------------------------------------
__global__ __launch_bounds__(256) void bucket_sort_kernel(
    const int* __restrict__ bbase, const unsigned int* __restrict__ pairs,
    const float* __restrict__ xfeat,
    int* __restrict__ off, int* __restrict__ sorted_src,
    float* __restrict__ agg1)
{
    __shared__ int lh[BKT_SIZE];     // histogram -> cursors
    __shared__ float laccum[BKT_SIZE];
    __shared__ int sdata[256];
    int b = blockIdx.x;
    int t = threadIdx.x;
    int base_node = b << BKT_BITS;
    int start = bbase[b];
    int end = bbase[b + 1];

    for (int i = t; i < BKT_SIZE; i += 256) { lh[i] = 0; laccum[i] = 0.0f; }
    __syncthreads();

    for (int e = start + t; e < end; e += 256)
        atomicAdd(&lh[pairs[e] & (BKT_SIZE - 1)], 1);
    __syncthreads();

    // exclusive scan of lh[1024]: 4 elems per thread
    int i0 = t * 4;
    int c0 = lh[i0], c1 = lh[i0 + 1], c2 = lh[i0 + 2], c3 = lh[i0 + 3];
    int s = c0 + c1 + c2 + c3;
    sdata[t] = s;
    __syncthreads();
    for (int o = 1; o < 256; o <<= 1) {
        int tmp = (t >= o) ? sdata[t - o] : 0;
        __syncthreads();
        sdata[t] += tmp;
        __syncthreads();
    }
    int run = start + sdata[t] - s;   // global exclusive prefix for elem i0
    int vals[4] = {c0, c1, c2, c3};
#pragma unroll
    for (int q = 0; q < 4; ++q) {
        int node = base_node + i0 + q;
        if (node < N_NODES) {
            off[node] = run;
            if (node == N_NODES - 1) off[N_NODES] = run + vals[q];
        }
        lh[i0 + q] = run;             // cursor
        run += vals[q];
    }
    __syncthreads();

    // place edges via LDS cursors + accumulate layer-1 aggregation
    for (int e = start + t; e < end; e += 256) {
        unsigned int p = pairs[e];
        int low = (int)(p & (BKT_SIZE - 1));
        int sidx = (int)(p >> BKT_BITS);
        int pos = atomicAdd(&lh[low], 1);
        sorted_src[pos] = sidx;
        atomicAdd(&laccum[low], xfeat[sidx]);
    }
    __syncthreads();

    for (int i = t; i < BKT_SIZE; i += 256) {
        int node = base_node + i;
        if (node < N_NODES) agg1[node] = laccum[i];
    }
}

// ---------------------------------------------------------------------------
// Gather: agg[i][j] = sum over edges of node i of h[src][j], G lanes per node.
// ---------------------------------------------------------------------------
template<int G>
__global__ __launch_bounds__(256) void gather_kernel(
    const int* __restrict__ off, const int* __restrict__ sorted_src,
    const float* __restrict__ h, float* __restrict__ agg)
{
    const int npb = 256 / G;
    int node = blockIdx.x * npb + threadIdx.x / G;
    int j = threadIdx.x % G;
    if (node >= N_NODES) return;
    int start = off[node];
    int end = off[node + 1];
    int gb = (threadIdx.x & 63) & ~(G - 1);   // group base lane within wave
    float acc = 0.0f;
    for (int base = start; base < end; base += G) {
        int e = base + j;
        int my = (e < end) ? sorted_src[e] : 0;
        int count = end - base;
        if (count > G) count = G;
        for (int t = 0; t < count; ++t) {
            int sb = __shfl(my, gb + t, 64);
            acc += h[(long)sb * G + j];
        }
    }
    agg[(long)node * G + j] = acc;
}

// ---------------------------------------------------------------------------
// Per-node transform: hout = relu(agg @ Wrel + brel + hin @ Wroot)
// ---------------------------------------------------------------------------
template<int DIN, int SIN, int DOUT, int SOUT>
__global__ __launch_bounds__(256) void transform_kernel(
    const float* __restrict__ agg,
    const float* __restrict__ hin,
    const float* __restrict__ Wrel,
    const float* __restrict__ brel,
    const float* __restrict__ Wroot,
    float* __restrict__ hout)
{
    __shared__ float sWrel[DIN * DOUT];
    __shared__ float sWroot[DIN * DOUT];
    __shared__ float sbrel[DOUT];
    for (int t = threadIdx.x; t < DIN * DOUT; t += blockDim.x) {
        sWrel[t] = Wrel[t];
        sWroot[t] = Wroot[t];
    }
    for (int t = threadIdx.x; t < DOUT; t += blockDim.x) sbrel[t] = brel[t];
    __syncthreads();

    int i = blockIdx.x * blockDim.x + threadIdx.x;
    if (i >= N_NODES) return;

    float a[DIN], x[DIN];
#pragma unroll
    for (int k = 0; k < DIN; ++k) {
        a[k] = agg[(long)i * SIN + k];
        x[k] = hin[(long)i * SIN + k];
    }
#pragma unroll
    for (int o = 0; o < DOUT; ++o) {
        float v = sbrel[o];
#pragma unroll
        for (int k = 0; k < DIN; ++k)
            v += a[k] * sWrel[k * DOUT + o] + x[k] * sWroot[k * DOUT + o];
        hout[(long)i * SOUT + o] = fmaxf(v, 0.0f);
    }
}

// ---------------------------------------------------------------------------
// Fused layer-4 transform + 3-layer MLP (agg/h3 padded to stride 16).
// ---------------------------------------------------------------------------
__global__ __launch_bounds__(256) void layer4_mlp_kernel(
    const float* __restrict__ agg,
    const float* __restrict__ h3,
    const float* __restrict__ g4Wrel,
    const float* __restrict__ g4brel,
    const float* __restrict__ g4Wroot,
    const float* __restrict__ fc1W,
    const float* __restrict__ fc1b,
    const float* __restrict__ fc2W,
    const float* __restrict__ fc2b,
    const float* __restrict__ fc3W,
    const float* __restrict__ fc3b,
    float* __restrict__ out)
{
    __shared__ float s[1680];
    float* sWrel  = s;            // 160
    float* sbrel  = s + 160;      // 16
    float* sWroot = s + 176;      // 160
    float* sfc1W  = s + 336;      // 512
    float* sfc1b  = s + 848;      // 32
    float* sfc2W  = s + 880;      // 512
    float* sfc2b  = s + 1392;     // 16
    float* sfc3W  = s + 1408;     // 256
    float* sfc3b  = s + 1664;     // 16

    for (int t = threadIdx.x; t < 160; t += blockDim.x) { sWrel[t] = g4Wrel[t]; sWroot[t] = g4Wroot[t]; }
    for (int t = threadIdx.x; t < 512; t += blockDim.x) { sfc1W[t] = fc1W[t]; sfc2W[t] = fc2W[t]; }
    for (int t = threadIdx.x; t < 256; t += blockDim.x) { sfc3W[t] = fc3W[t]; }
    for (int t = threadIdx.x; t < 32;  t += blockDim.x) { sfc1b[t] = fc1b[t]; }
    for (int t = threadIdx.x; t < 16;  t += blockDim.x) { sbrel[t] = g4brel[t]; sfc2b[t] = fc2b[t]; sfc3b[t] = fc3b[t]; }
    __syncthreads();

    int i = blockIdx.x * blockDim.x + threadIdx.x;
    if (i >= N_NODES) return;

    float a[10], x[10];
#pragma unroll
    for (int k = 0; k < 10; ++k) {
        a[k] = agg[(long)i * 16 + k];
        x[k] = h3[(long)i * 16 + k];
    }

    float h4[16];
#pragma unroll
    for (int o = 0; o < 16; ++o) {
        float v = sbrel[o];
#pragma unroll
        for (int k = 0; k < 10; ++k)
            v += a[k] * sWrel[k * 16 + o] + x[k] * sWroot[k * 16 + o];
        h4[o] = fmaxf(v, 0.0f);
    }

    float m1[32];
#pragma unroll
    for (int o = 0; o < 32; ++o) {
        float v = sfc1b[o];
#pragma unroll
        for (int k = 0; k < 16; ++k) v += h4[k] * sfc1W[k * 32 + o];
        m1[o] = fmaxf(v, 0.0f);
    }

    float m2[16];
#pragma unroll
    for (int o = 0; o < 16; ++o) {
        float v = sfc2b[o];
#pragma unroll
        for (int k = 0; k < 32; ++k) v += m1[k] * sfc2W[k * 16 + o];
        m2[o] = fmaxf(v, 0.0f);
    }

    float r[16];
#pragma unroll
    for (int o = 0; o < 16; ++o) {
        float v = sfc3b[o];
#pragma unroll
        for (int k = 0; k < 16; ++k) v += m2[k] * sfc3W[k * 16 + o];
        r[o] = v;
    }
    float4* op = (float4*)(out + (long)i * 16);
#pragma unroll
    for (int q = 0; q < 4; ++q)
        op[q] = make_float4(r[q * 4 + 0], r[q * 4 + 1], r[q * 4 + 2], r[q * 4 + 3]);
}

// ---------------------------------------------------------------------------
extern "C" void kernel_launch(void* const* d_in, const int* in_sizes, int n_in,
                              void* d_out, int out_size, void* d_ws, size_t ws_size,
                              hipStream_t stream) {
    const float* x        = (const float*)d_in[0];
    const int*   ei       = (const int*)d_in[1];
    const float* g1_Wrel  = (const float*)d_in[2];
    const float* g1_brel  = (const float*)d_in[3];
    const float* g1_Wroot = (const float*)d_in[4];
    const float* g2_Wrel  = (const float*)d_in[5];
    const float* g2_brel  = (const float*)d_in[6];
    const float* g2_Wroot = (const float*)d_in[7];
    const float* g3_Wrel  = (const float*)d_in[8];
    const float* g3_brel  = (const float*)d_in[9];
    const float* g3_Wroot = (const float*)d_in[10];
    const float* g4_Wrel  = (const float*)d_in[11];
    const float* g4_brel  = (const float*)d_in[12];
    const float* g4_Wroot = (const float*)d_in[13];
    const float* fc1_W    = (const float*)d_in[14];
    const float* fc1_b    = (const float*)d_in[15];
    const float* fc2_W    = (const float*)d_in[16];
    const float* fc2_b    = (const float*)d_in[17];
    const float* fc3_W    = (const float*)d_in[18];
    const float* fc3_b    = (const float*)d_in[19];
    float* out = (float*)d_out;

    const int* srcp = ei;
    const int* dstp = ei + N_EDGES;

    // ---- workspace layout (256B aligned) ----
    char* p = (char*)d_ws;
    auto alloc = [&](size_t bytes) {
        char* r = p;
        p += (bytes + 255) & ~(size_t)255;
        return r;
    };
    int*   off        = (int*)  alloc((size_t)(N_NODES + 1) * 4);    //  2 MB
    int*   bhist      = (int*)  alloc((size_t)NBUCKET * 4);
    int*   bbase      = (int*)  alloc((size_t)(NBUCKET + 1) * 4);
    int*   bcur       = (int*)  alloc((size_t)NBUCKET * 4);
    float* h1p        = (float*)alloc((size_t)N_NODES * 4 * 4);      //  8 MB
    float* h2p        = (float*)alloc((size_t)N_NODES * 8 * 4);      // 16 MB
    float* h3p        = (float*)alloc((size_t)N_NODES * 16 * 4);     // 32 MB
    float* agg        = (float*)alloc((size_t)N_NODES * 16 * 4);     // 32 MB
    int*   sorted_src = (int*)  alloc((size_t)N_EDGES * 4);          // 64 MB
    // pairs (64 MB) is transient: alias h1p (spans h1p+h2p+h3p+first 8MB of
    // agg; all dead/unwritten until bucket_sort completes).
    unsigned int* pairs = (unsigned int*)h1p;
    // agg1 (2 MB) must NOT overlap pairs' 64MB span: place 16MB into agg.
    float* agg1 = agg + (size_t)4 * 1024 * 1024;

    const int TB = 256;
    const int node_blocks = (N_NODES + TB - 1) / TB;

    // ---- build CSR (binned counting sort by dst) + fused layer-1 agg ----
    hipMemsetAsync(bhist, 0, (size_t)NBUCKET * 4, stream);
    bucket_hist_kernel<<<BIN_NBLK, TB, 0, stream>>>(dstp, bhist);
    bucket_scan_kernel<<<1, 512, 0, stream>>>(bhist, bbase, bcur);
    bin_kernel<<<BIN_NBLK, TB, 0, stream>>>(srcp, dstp, bcur, pairs);
    bucket_sort_kernel<<<NBUCKET, TB, 0, stream>>>(bbase, pairs, x, off, sorted_src, agg1);

    // ---- layer 1: din=1 -> dout=4 (stride 4); agg precomputed ----
    transform_kernel<1, 1, 4, 4><<<node_blocks, TB, 0, stream>>>(
        agg1, x, g1_Wrel, g1_brel, g1_Wroot, h1p);

    // ---- layer 2: din=4 (stride 4) -> dout=7 (stride 8) ----
    gather_kernel<4><<<(N_NODES + 63) / 64, TB, 0, stream>>>(off, sorted_src, h1p, agg);
    transform_kernel<4, 4, 7, 8><<<node_blocks, TB, 0, stream>>>(
        agg, h1p, g2_Wrel, g2_brel, g2_Wroot, h2p);

    // ---- layer 3: din=7 (stride 8) -> dout=10 (stride 16) ----
    gather_kernel<8><<<(N_NODES + 31) / 32, TB, 0, stream>>>(off, sorted_src, h2p, agg);
    transform_kernel<7, 8, 10, 16><<<node_blocks, TB, 0, stream>>>(
        agg, h2p, g3_Wrel, g3_brel, g3_Wroot, h3p);

    // ---- layer 4 (din=10, stride 16) + MLP, fused ----
    gather_kernel<16><<<(N_NODES + 15) / 16, TB, 0, stream>>>(off, sorted_src, h3p, agg);
    layer4_mlp_kernel<<<node_blocks, TB, 0, stream>>>(
        agg, h3p, g4_Wrel, g4_brel, g4_Wroot,
        fc1_W, fc1_b, fc2_W, fc2_b, fc3_W, fc3_b, out);
}